// Round 1
// baseline (514.606 us; speedup 1.0000x reference)
//
#include <hip/hip_runtime.h>

// JointLoss on MI355X.
// N=8192 samples, D=256 embedding dim. Output: 1 fp32 scalar.
//
// ws layout (bytes):
//   [0,       32768)   rank[N]    int   (atomic-accumulated; final = permutation 0..N-1)
//   [32768,   65536)   at_risk[N] float (atomic-accumulated)
//   [65536,   65600)   accums: [0]=cox_sum, [1]=cnt(int), [2]=sim_sum(1-cos), [3]=contrast_sum
//   [131072,  131072+4M)  packed wsi  bf16, k-step-major: pk[ks][row][32] (ks=k/32)
//   [131072+4M, +8M)      packed omic bf16
// Total ~8.3 MB of ws. Only first 65600 B needs zeroing (hipMemsetAsync).

#define NN 8192
#define DD 256

typedef __attribute__((ext_vector_type(8))) short bf16x8; // 8 bf16 = 4 VGPRs (guide-verified frag type)
typedef __attribute__((ext_vector_type(4))) float f32x4;

__device__ inline unsigned short f2bf(float f) {
  union { float f; unsigned int u; } v;
  v.f = f;
  unsigned int u = v.u;
  unsigned int r = (u + 0x7fffu + ((u >> 16) & 1u)) >> 16; // RNE
  return (unsigned short)r;
}

// ---------------------------------------------------------------------------
// K1: O(N^2) brute-force rank + at-risk sums. Replaces sort + cumsum.
//   rank_i    = #{j : t_j < t_i  or (t_j==t_i and j<i)}   (stable, permutation)
//   at_risk_i = sum over the complement set (t_j>t_i or (t_j==t_i and j<=i),
//               includes self) of exp(clip(lr_j,-10,10))  -- matches
//               cumsum(exp(slr)) of stable argsort(-times).
// grid (32 i-blocks, 8 j-chunks) x 256 thr.
// ---------------------------------------------------------------------------
__global__ void __launch_bounds__(256) k_rank_atrisk(
    const float* __restrict__ times, const float* __restrict__ lr,
    int* __restrict__ rank, float* __restrict__ at_risk) {
  __shared__ __align__(16) float st[1024];
  __shared__ __align__(16) float se[1024];
  const int tid = threadIdx.x;
  const int i = blockIdx.x * 256 + tid;
  const int jbase = blockIdx.y * 1024;
  for (int p = tid; p < 1024; p += 256) {
    float t = times[jbase + p];
    float l = lr[jbase + p];
    l = fminf(fmaxf(l, -10.f), 10.f);
    st[p] = t;
    se[p] = expf(l);
  }
  __syncthreads();
  const float ti = times[i];
  int rk = 0;
  float ar = 0.f;
  for (int p4 = 0; p4 < 1024; p4 += 4) {
    float4 tv = *(const float4*)&st[p4];
    float4 ev = *(const float4*)&se[p4];
    const int j0 = jbase + p4;
#define K1_STEP(c, jo)                                              \
    {                                                               \
      bool c1 = (c < ti) || ((c == ti) && ((j0 + jo) < i));         \
      rk += c1 ? 1 : 0;                                             \
      ar += c1 ? 0.f : ((jo == 0) ? ev.x : (jo == 1) ? ev.y         \
                         : (jo == 2) ? ev.z : ev.w);                \
    }
    K1_STEP(tv.x, 0) K1_STEP(tv.y, 1) K1_STEP(tv.z, 2) K1_STEP(tv.w, 3)
#undef K1_STEP
  }
  atomicAdd(&rank[i], rk);
  atomicAdd(&at_risk[i], ar);
}

// ---------------------------------------------------------------------------
// K2: per-row (one wave per row): norms, cos-sim term, Cox li term,
//     normalize -> bf16 -> scatter-write into rank-permuted packed layout.
// grid 2048 x 256 thr (4 waves).
// ---------------------------------------------------------------------------
__global__ void __launch_bounds__(256) k_rows(
    const float* __restrict__ lr, const int* __restrict__ censor,
    const float* __restrict__ wsi, const float* __restrict__ omic,
    const int* __restrict__ rank, const float* __restrict__ at_risk,
    unsigned short* __restrict__ pw, unsigned short* __restrict__ po,
    float* __restrict__ acc) {
  const int tid = threadIdx.x;
  const int lane = tid & 63;
  const int i = blockIdx.x * 4 + (tid >> 6);
  const float4 w = ((const float4*)(wsi + (size_t)i * DD))[lane];
  const float4 o = ((const float4*)(omic + (size_t)i * DD))[lane];
  float nw = w.x * w.x + w.y * w.y + w.z * w.z + w.w * w.w;
  float no = o.x * o.x + o.y * o.y + o.z * o.z + o.w * o.w;
  float dd = w.x * o.x + w.y * o.y + w.z * o.z + w.w * o.w;
  for (int m = 1; m < 64; m <<= 1) {
    nw += __shfl_xor(nw, m);
    no += __shfl_xor(no, m);
    dd += __shfl_xor(dd, m);
  }
  const float nws = sqrtf(nw), nos = sqrtf(no);
  if (lane == 0) {
    float c = dd / (fmaxf(nws, 1e-8f) * fmaxf(nos, 1e-8f));
    c = fminf(fmaxf(c, -1.f), 1.f);
    atomicAdd(&acc[2], 1.f - c);
    float l = fminf(fmaxf(lr[i], -10.f), 10.f);
    float li = l - logf(at_risk[i] + 1e-15f);
    if (censor[i] == 1) {
      atomicAdd(&acc[0], li);
      atomicAdd((int*)acc + 1, 1);
    }
  }
  const int r = rank[i]; // permuted row position; rank>>11 == risk group
  const float iw = 1.f / fmaxf(nws, 1e-12f);
  const float io = 1.f / fmaxf(nos, 1e-12f);
  ushort4 zw, zo;
  zw.x = f2bf(w.x * iw); zw.y = f2bf(w.y * iw); zw.z = f2bf(w.z * iw); zw.w = f2bf(w.w * iw);
  zo.x = f2bf(o.x * io); zo.y = f2bf(o.y * io); zo.z = f2bf(o.z * io); zo.w = f2bf(o.w * io);
  // lane covers k = lane*4..lane*4+3 -> ks = lane>>3, offset (lane&7)*4 within 32-chunk
  const size_t off = ((size_t)(lane >> 3) * NN + r) * 32 + (lane & 7) * 4;
  *(ushort4*)(pw + off) = zw;
  *(ushort4*)(po + off) = zo;
}

// ---------------------------------------------------------------------------
// K3: contrastive loss. grid (128 row-blocks, 2 matrices) x 512 thr (8 waves).
// One block per CU. Each wave: 64 rows A-resident in regs (full K=256),
// sweeps 64 column-tiles of 16 (stride 8 across waves). B-frags loaded
// directly from L2 (no LDS: A-resident means B bytes are used exactly once).
// Per tile: 8 k-step MFMAs x 4 row-tiles, then exp(sim-10) accumulated into
// per-group sums (columns are group-contiguous blocks of 2048). Diagonal
// excluded exactly in-register.
// ---------------------------------------------------------------------------
__device__ inline void flush_group(float s[4][4], int g, int lane,
                                   float* __restrict__ s_lds) {
#pragma unroll
  for (int rt = 0; rt < 4; ++rt)
#pragma unroll
    for (int r = 0; r < 4; ++r) {
      float v = s[rt][r];
      for (int m = 1; m < 16; m <<= 1) v += __shfl_xor(v, m);
      if ((lane & 15) == 0) {
        int row = rt * 16 + (lane >> 4) * 4 + r; // C/D layout: row=(lane>>4)*4+reg
        atomicAdd(&s_lds[row * 4 + g], v);
      }
      s[rt][r] = 0.f;
    }
}

__global__ void __launch_bounds__(512, 2) k_contrast(
    const unsigned short* __restrict__ pw, const unsigned short* __restrict__ po,
    float* __restrict__ acc) {
  __shared__ float s_lds[64 * 4];
  const int tid = threadIdx.x;
  const int lane = tid & 63;
  const int wv = tid >> 6; // 0..7
  const int rb = blockIdx.x;
  const unsigned short* __restrict__ pk = (blockIdx.y == 0) ? pw : po;
  if (tid < 256) s_lds[tid] = 0.f;
  __syncthreads();

  const int lo = lane & 15, q = lane >> 4;
  const int rowbase = rb * 64;

  // A fragments: 4 row-tiles x 8 k-steps, register-resident (128 VGPRs)
  bf16x8 afrag[4][8];
#pragma unroll
  for (int rt = 0; rt < 4; ++rt) {
    const size_t row = rowbase + rt * 16 + lo;
#pragma unroll
    for (int ks = 0; ks < 8; ++ks)
      afrag[rt][ks] = *(const bf16x8*)(pk + ((size_t)ks * NN + row) * 32 + q * 8);
  }

  float s[4][4] = {{0.f}};
  int curg = 0; // first tile t=wv has group (wv)>>7 == 0

  // preload B for first tile
  bf16x8 bcur[8];
  {
    const size_t col = (size_t)wv * 16 + lo;
#pragma unroll
    for (int ks = 0; ks < 8; ++ks)
      bcur[ks] = *(const bf16x8*)(pk + ((size_t)ks * NN + col) * 32 + q * 8);
  }

#pragma unroll 1
  for (int k = 0; k < 64; ++k) {
    const int t = wv + k * 8;
    const int g = t >> 7; // group = (t*16)>>11, groups are exactly 2048 cols
    if (g != curg) {
      flush_group(s, curg, lane, s_lds);
      curg = g;
    }
    // prefetch next tile's B while MFMAs run
    bf16x8 bnxt[8];
    if (k < 63) {
      const size_t ncol = (size_t)(t + 8) * 16 + lo;
#pragma unroll
      for (int ks = 0; ks < 8; ++ks)
        bnxt[ks] = *(const bf16x8*)(pk + ((size_t)ks * NN + ncol) * 32 + q * 8);
    }
    f32x4 accv[4];
#pragma unroll
    for (int rt = 0; rt < 4; ++rt) { f32x4 z = {0.f, 0.f, 0.f, 0.f}; accv[rt] = z; }
#pragma unroll
    for (int ks = 0; ks < 8; ++ks)
#pragma unroll
      for (int rt = 0; rt < 4; ++rt)
        accv[rt] = __builtin_amdgcn_mfma_f32_16x16x32_bf16(afrag[rt][ks], bcur[ks], accv[rt], 0, 0, 0);

    const int col = t * 16 + lo;
    const bool diag = ((t >> 2) == rb); // tile overlaps this block's rows
#pragma unroll
    for (int rt = 0; rt < 4; ++rt)
#pragma unroll
      for (int r = 0; r < 4; ++r) {
        // sim = dot/0.1; shifted LSE with fixed max 10 (unit vectors => sim<=10)
        float e = __expf(accv[rt][r] * 10.f - 10.f);
        if (diag) {
          int row = rowbase + rt * 16 + q * 4 + r;
          if (row == col) e = 0.f;
        }
        s[rt][r] += e;
      }
#pragma unroll
    for (int ks = 0; ks < 8; ++ks) bcur[ks] = bnxt[ks];
  }
  flush_group(s, curg, lane, s_lds);
  __syncthreads();

  if (tid < 64) {
    const float s0 = s_lds[tid * 4 + 0], s1 = s_lds[tid * 4 + 1];
    const float s2 = s_lds[tid * 4 + 2], s3 = s_lds[tid * 4 + 3];
    const int g = (rowbase + tid) >> 11; // group of permuted row
    const float sp = s_lds[tid * 4 + g];
    // loss = lse_all - lse_pos = log(sum_all) - log(sum_pos)  (shifts cancel)
    float loss = logf(s0 + s1 + s2 + s3) - logf(sp);
    for (int m = 1; m < 64; m <<= 1) loss += __shfl_xor(loss, m);
    if (tid == 0) atomicAdd(&acc[3], loss);
  }
}

// ---------------------------------------------------------------------------
// K4: combine scalar. All 8192 rows are contrast-valid (groups of 2048).
// ---------------------------------------------------------------------------
__global__ void k_final(const float* __restrict__ acc, float* __restrict__ out) {
  if (threadIdx.x == 0 && blockIdx.x == 0) {
    float cnt = fmaxf((float)((const int*)acc)[1], 1.f);
    float cox = -acc[0] / cnt;
    float sim = acc[2] / (float)NN;
    float contrast = 0.1f * 0.5f * acc[3] / (float)NN;
    out[0] = cox + sim + contrast;
  }
}

extern "C" void kernel_launch(void* const* d_in, const int* in_sizes, int n_in,
                              void* d_out, int out_size, void* d_ws, size_t ws_size,
                              hipStream_t stream) {
  const float* lr = (const float*)d_in[0];
  const float* times = (const float*)d_in[1];
  const int* censor = (const int*)d_in[2];
  const float* wsi = (const float*)d_in[3];
  const float* omic = (const float*)d_in[4];
  float* out = (float*)d_out;

  char* ws = (char*)d_ws;
  int* rank = (int*)ws;
  float* at_risk = (float*)(ws + 32768);
  float* acc = (float*)(ws + 65536);
  unsigned short* pw = (unsigned short*)(ws + 131072);
  unsigned short* po = (unsigned short*)(ws + 131072 + 4194304);

  hipMemsetAsync(d_ws, 0, 65536 + 256, stream);
  k_rank_atrisk<<<dim3(32, 8), 256, 0, stream>>>(times, lr, rank, at_risk);
  k_rows<<<2048, 256, 0, stream>>>(lr, censor, wsi, omic, rank, at_risk, pw, po, acc);
  k_contrast<<<dim3(128, 2), 512, 0, stream>>>(pw, po, acc);
  k_final<<<1, 1, 0, stream>>>(acc, out);
}

// Round 2
// 225.834 us; speedup vs baseline: 2.2787x; 2.2787x over previous
//
#include <hip/hip_runtime.h>

// JointLoss on MI355X.
// N=8192 samples, D=256 embedding dim. Output: 1 fp32 scalar.
//
// ws layout (bytes):
//   [0,       32768)   rank[N]    int   (atomic-accumulated; final = permutation 0..N-1)
//   [32768,   65536)   at_risk[N] float (atomic-accumulated)
//   [65536,   66560)   slot accumulators, 64 slots x 4 quantities (cox, cnt, sim, contrast)
//   [131072,  131072+4M)  packed wsi  bf16, k-step-major: pk[ks][row][32] (ks=k/32)
//   [131072+4M, +8M)      packed omic bf16
// R1 lesson: 24k same-address atomics serialized -> 306us stall. Now: block-
// reduce + 64-slot-spread atomics (Guideline 12).

#define NN 8192
#define DD 256
#define NSLOT 64

typedef __attribute__((ext_vector_type(8))) short bf16x8; // 8 bf16 = 4 VGPRs
typedef __attribute__((ext_vector_type(4))) float f32x4;

__device__ inline unsigned short f2bf(float f) {
  union { float f; unsigned int u; } v;
  v.f = f;
  unsigned int u = v.u;
  unsigned int r = (u + 0x7fffu + ((u >> 16) & 1u)) >> 16; // RNE
  return (unsigned short)r;
}

// ---------------------------------------------------------------------------
// K1: O(N^2) brute-force rank + at-risk sums. Replaces sort + cumsum.
//   rank_i    = #{j : t_j < t_i  or (t_j==t_i and j<i)}   (stable, permutation)
//   at_risk_i = sum over complement (incl. self) of exp(clip(lr_j,-10,10))
//               == cumsum(exp(slr)) of stable argsort(-times).
// grid (32 i-blocks, 8 j-chunks) x 256 thr. Atomics here are per-i distinct
// addresses (8 adds each) -- parallel across L2, not contended.
// ---------------------------------------------------------------------------
__global__ void __launch_bounds__(256) k_rank_atrisk(
    const float* __restrict__ times, const float* __restrict__ lr,
    int* __restrict__ rank, float* __restrict__ at_risk) {
  __shared__ __align__(16) float st[1024];
  __shared__ __align__(16) float se[1024];
  const int tid = threadIdx.x;
  const int i = blockIdx.x * 256 + tid;
  const int jbase = blockIdx.y * 1024;
  for (int p = tid; p < 1024; p += 256) {
    float t = times[jbase + p];
    float l = lr[jbase + p];
    l = fminf(fmaxf(l, -10.f), 10.f);
    st[p] = t;
    se[p] = expf(l);
  }
  __syncthreads();
  const float ti = times[i];
  int rk = 0;
  float ar = 0.f;
  for (int p4 = 0; p4 < 1024; p4 += 4) {
    float4 tv = *(const float4*)&st[p4];
    float4 ev = *(const float4*)&se[p4];
    const int j0 = jbase + p4;
#define K1_STEP(c, jo)                                              \
    {                                                               \
      bool c1 = (c < ti) || ((c == ti) && ((j0 + jo) < i));         \
      rk += c1 ? 1 : 0;                                             \
      ar += c1 ? 0.f : ((jo == 0) ? ev.x : (jo == 1) ? ev.y         \
                         : (jo == 2) ? ev.z : ev.w);                \
    }
    K1_STEP(tv.x, 0) K1_STEP(tv.y, 1) K1_STEP(tv.z, 2) K1_STEP(tv.w, 3)
#undef K1_STEP
  }
  atomicAdd(&rank[i], rk);
  atomicAdd(&at_risk[i], ar);
}

// ---------------------------------------------------------------------------
// K2: per-row (one wave per row): norms, cos-sim term, Cox li term,
//     normalize -> bf16 -> scatter-write into rank-permuted packed layout.
// grid 2048 x 256 thr (4 waves). Scalar sums block-reduced through LDS, then
// ONE wave-level atomic per quantity into slot (blockIdx&63).
// ---------------------------------------------------------------------------
__global__ void __launch_bounds__(256) k_rows(
    const float* __restrict__ lr, const int* __restrict__ censor,
    const float* __restrict__ wsi, const float* __restrict__ omic,
    const int* __restrict__ rank, const float* __restrict__ at_risk,
    unsigned short* __restrict__ pw, unsigned short* __restrict__ po,
    float* __restrict__ slots) {
  __shared__ float red[4][3];
  const int tid = threadIdx.x;
  const int lane = tid & 63;
  const int wv = tid >> 6;
  const int i = blockIdx.x * 4 + wv;
  const float4 w = ((const float4*)(wsi + (size_t)i * DD))[lane];
  const float4 o = ((const float4*)(omic + (size_t)i * DD))[lane];
  float nw = w.x * w.x + w.y * w.y + w.z * w.z + w.w * w.w;
  float no = o.x * o.x + o.y * o.y + o.z * o.z + o.w * o.w;
  float dd = w.x * o.x + w.y * o.y + w.z * o.z + w.w * o.w;
  for (int m = 1; m < 64; m <<= 1) {
    nw += __shfl_xor(nw, m);
    no += __shfl_xor(no, m);
    dd += __shfl_xor(dd, m);
  }
  const float nws = sqrtf(nw), nos = sqrtf(no);
  if (lane == 0) {
    float c = dd / (fmaxf(nws, 1e-8f) * fmaxf(nos, 1e-8f));
    c = fminf(fmaxf(c, -1.f), 1.f);
    float l = fminf(fmaxf(lr[i], -10.f), 10.f);
    float li = l - logf(at_risk[i] + 1e-15f);
    bool cen = (censor[i] == 1);
    red[wv][0] = cen ? li : 0.f;   // cox sum
    red[wv][1] = cen ? 1.f : 0.f;  // count (exact in fp32)
    red[wv][2] = 1.f - c;          // sim sum
  }
  const int r = rank[i]; // permuted row position; rank>>11 == risk group
  const float iw = 1.f / fmaxf(nws, 1e-12f);
  const float io = 1.f / fmaxf(nos, 1e-12f);
  ushort4 zw, zo;
  zw.x = f2bf(w.x * iw); zw.y = f2bf(w.y * iw); zw.z = f2bf(w.z * iw); zw.w = f2bf(w.w * iw);
  zo.x = f2bf(o.x * io); zo.y = f2bf(o.y * io); zo.z = f2bf(o.z * io); zo.w = f2bf(o.w * io);
  // lane covers k = lane*4..lane*4+3 -> ks = lane>>3, offset (lane&7)*4 within 32-chunk
  const size_t off = ((size_t)(lane >> 3) * NN + r) * 32 + (lane & 7) * 4;
  *(ushort4*)(pw + off) = zw;
  *(ushort4*)(po + off) = zo;
  __syncthreads();
  if (tid < 3) {
    float v = red[0][tid] + red[1][tid] + red[2][tid] + red[3][tid];
    atomicAdd(&slots[tid * NSLOT + (blockIdx.x & (NSLOT - 1))], v);
  }
}

// ---------------------------------------------------------------------------
// K3: contrastive loss. grid (128 row-blocks, 2 matrices) x 512 thr (8 waves).
// One block per CU. Each wave: 64 rows A-resident in regs (full K=256),
// sweeps 64 column-tiles of 16 (stride 8 across waves). B-frags loaded
// directly from L2 (no LDS: A-resident means B bytes are used exactly once).
// Per tile: 8 k-step MFMAs x 4 row-tiles, then exp(sim-10) accumulated into
// per-group sums (columns are group-contiguous blocks of 2048). Diagonal
// excluded exactly in-register.
// ---------------------------------------------------------------------------
__device__ inline void flush_group(float s[4][4], int g, int lane,
                                   float* __restrict__ s_lds) {
#pragma unroll
  for (int rt = 0; rt < 4; ++rt)
#pragma unroll
    for (int r = 0; r < 4; ++r) {
      float v = s[rt][r];
      for (int m = 1; m < 16; m <<= 1) v += __shfl_xor(v, m);
      if ((lane & 15) == 0) {
        int row = rt * 16 + (lane >> 4) * 4 + r; // C/D layout: row=(lane>>4)*4+reg
        atomicAdd(&s_lds[row * 4 + g], v);       // LDS atomic, per-block
      }
      s[rt][r] = 0.f;
    }
}

__global__ void __launch_bounds__(512, 2) k_contrast(
    const unsigned short* __restrict__ pw, const unsigned short* __restrict__ po,
    float* __restrict__ slots) {
  __shared__ float s_lds[64 * 4];
  const int tid = threadIdx.x;
  const int lane = tid & 63;
  const int wv = tid >> 6; // 0..7
  const int rb = blockIdx.x;
  const unsigned short* __restrict__ pk = (blockIdx.y == 0) ? pw : po;
  if (tid < 256) s_lds[tid] = 0.f;
  __syncthreads();

  const int lo = lane & 15, q = lane >> 4;
  const int rowbase = rb * 64;

  // A fragments: 4 row-tiles x 8 k-steps, register-resident (128 VGPRs)
  bf16x8 afrag[4][8];
#pragma unroll
  for (int rt = 0; rt < 4; ++rt) {
    const size_t row = rowbase + rt * 16 + lo;
#pragma unroll
    for (int ks = 0; ks < 8; ++ks)
      afrag[rt][ks] = *(const bf16x8*)(pk + ((size_t)ks * NN + row) * 32 + q * 8);
  }

  float s[4][4] = {{0.f}};
  int curg = 0; // first tile t=wv has group (wv)>>7 == 0

  // preload B for first tile
  bf16x8 bcur[8];
  {
    const size_t col = (size_t)wv * 16 + lo;
#pragma unroll
    for (int ks = 0; ks < 8; ++ks)
      bcur[ks] = *(const bf16x8*)(pk + ((size_t)ks * NN + col) * 32 + q * 8);
  }

#pragma unroll 1
  for (int k = 0; k < 64; ++k) {
    const int t = wv + k * 8;
    const int g = t >> 7; // group = (t*16)>>11, groups are exactly 2048 cols
    if (g != curg) {
      flush_group(s, curg, lane, s_lds);
      curg = g;
    }
    // prefetch next tile's B while MFMAs run
    bf16x8 bnxt[8];
    if (k < 63) {
      const size_t ncol = (size_t)(t + 8) * 16 + lo;
#pragma unroll
      for (int ks = 0; ks < 8; ++ks)
        bnxt[ks] = *(const bf16x8*)(pk + ((size_t)ks * NN + ncol) * 32 + q * 8);
    }
    f32x4 accv[4];
#pragma unroll
    for (int rt = 0; rt < 4; ++rt) { f32x4 z = {0.f, 0.f, 0.f, 0.f}; accv[rt] = z; }
#pragma unroll
    for (int ks = 0; ks < 8; ++ks)
#pragma unroll
      for (int rt = 0; rt < 4; ++rt)
        accv[rt] = __builtin_amdgcn_mfma_f32_16x16x32_bf16(afrag[rt][ks], bcur[ks], accv[rt], 0, 0, 0);

    const int col = t * 16 + lo;
    const bool diag = ((t >> 2) == rb); // tile overlaps this block's rows
#pragma unroll
    for (int rt = 0; rt < 4; ++rt)
#pragma unroll
      for (int r = 0; r < 4; ++r) {
        // sim = dot/0.1; shifted LSE with fixed max 10 (unit vectors => sim<=10)
        float e = __expf(accv[rt][r] * 10.f - 10.f);
        if (diag) {
          int row = rowbase + rt * 16 + q * 4 + r;
          if (row == col) e = 0.f;
        }
        s[rt][r] += e;
      }
#pragma unroll
    for (int ks = 0; ks < 8; ++ks) bcur[ks] = bnxt[ks];
  }
  flush_group(s, curg, lane, s_lds);
  __syncthreads();

  if (tid < 64) {
    const float s0 = s_lds[tid * 4 + 0], s1 = s_lds[tid * 4 + 1];
    const float s2 = s_lds[tid * 4 + 2], s3 = s_lds[tid * 4 + 3];
    const int g = (rowbase + tid) >> 11; // group of permuted row
    const float sp = s_lds[tid * 4 + g];
    // loss = lse_all - lse_pos = log(sum_all) - log(sum_pos)  (shifts cancel)
    float loss = logf(s0 + s1 + s2 + s3) - logf(sp);
    for (int m = 1; m < 64; m <<= 1) loss += __shfl_xor(loss, m);
    if (tid == 0) atomicAdd(&slots[3 * NSLOT + (rb & (NSLOT - 1))], loss);
  }
}

// ---------------------------------------------------------------------------
// K4: reduce 64 slots per quantity, combine scalar. One wave.
// ---------------------------------------------------------------------------
__global__ void k_final(const float* __restrict__ slots, float* __restrict__ out) {
  const int lane = threadIdx.x & 63;
  float cox_s = (lane < NSLOT) ? slots[0 * NSLOT + lane] : 0.f;
  float cnt_s = (lane < NSLOT) ? slots[1 * NSLOT + lane] : 0.f;
  float sim_s = (lane < NSLOT) ? slots[2 * NSLOT + lane] : 0.f;
  float con_s = (lane < NSLOT) ? slots[3 * NSLOT + lane] : 0.f;
  for (int m = 1; m < 64; m <<= 1) {
    cox_s += __shfl_xor(cox_s, m);
    cnt_s += __shfl_xor(cnt_s, m);
    sim_s += __shfl_xor(sim_s, m);
    con_s += __shfl_xor(con_s, m);
  }
  if (lane == 0) {
    float cnt = fmaxf(cnt_s, 1.f);
    float cox = -cox_s / cnt;
    float sim = sim_s / (float)NN;
    float contrast = 0.1f * 0.5f * con_s / (float)NN;
    out[0] = cox + sim + contrast;
  }
}

extern "C" void kernel_launch(void* const* d_in, const int* in_sizes, int n_in,
                              void* d_out, int out_size, void* d_ws, size_t ws_size,
                              hipStream_t stream) {
  const float* lr = (const float*)d_in[0];
  const float* times = (const float*)d_in[1];
  const int* censor = (const int*)d_in[2];
  const float* wsi = (const float*)d_in[3];
  const float* omic = (const float*)d_in[4];
  float* out = (float*)d_out;

  char* ws = (char*)d_ws;
  int* rank = (int*)ws;
  float* at_risk = (float*)(ws + 32768);
  float* slots = (float*)(ws + 65536);
  unsigned short* pw = (unsigned short*)(ws + 131072);
  unsigned short* po = (unsigned short*)(ws + 131072 + 4194304);

  hipMemsetAsync(d_ws, 0, 65536 + 4 * NSLOT * 4, stream);
  k_rank_atrisk<<<dim3(32, 8), 256, 0, stream>>>(times, lr, rank, at_risk);
  k_rows<<<2048, 256, 0, stream>>>(lr, censor, wsi, omic, rank, at_risk, pw, po, slots);
  k_contrast<<<dim3(128, 2), 512, 0, stream>>>(pw, po, slots);
  k_final<<<1, 64, 0, stream>>>(slots, out);
}

// Round 3
// 209.445 us; speedup vs baseline: 2.4570x; 1.0782x over previous
//
#include <hip/hip_runtime.h>

// JointLoss on MI355X.
// N=8192 samples, D=256 embedding dim. Output: 1 fp32 scalar.
//
// ws layout (bytes):
//   [0,       32768)    rank[N]    int   (atomic-accumulated; final = permutation 0..N-1)
//   [32768,   65536)    at_risk[N] float (atomic-accumulated)
//   [65536,   66560)    slot accumulators, 64 slots x 4 quantities (cox, cnt, sim, contrast)
//   [131072,  131072+4M)   packed wsi  bf16, k-step-major: pk[ks][row][32] (ks=k/32)
//   [131072+4M, +8M)       packed omic bf16
//   [131072+8M, +8M+256K)  gsum[2][8192][4] float: per-(matrix,row,group) exp-sums
//
// R1 lesson: same-address atomics serialize (~12ns each) -> slot-spread.
// R2 lesson: k_contrast with 64-row blocks streams 1 GB of B from L2/LLC
//   (8 MB working set vs 4 MB L2/XCD) -> LLC-latency bound at 100us. Now:
//   512-row blocks, B staged once per block in double-buffered LDS -> 128 MB.

#define NN 8192
#define DD 256
#define NSLOT 64

typedef __attribute__((ext_vector_type(8))) short bf16x8; // 8 bf16 = 4 VGPRs
typedef __attribute__((ext_vector_type(8))) unsigned short ush8;
typedef __attribute__((ext_vector_type(4))) float f32x4;

__device__ inline unsigned short f2bf(float f) {
  union { float f; unsigned int u; } v;
  v.f = f;
  unsigned int u = v.u;
  unsigned int r = (u + 0x7fffu + ((u >> 16) & 1u)) >> 16; // RNE
  return (unsigned short)r;
}

// ---------------------------------------------------------------------------
// K1: O(N^2) brute-force rank + at-risk sums. Replaces sort + cumsum.
//   rank_i    = #{j : t_j < t_i  or (t_j==t_i and j<i)}   (stable, permutation)
//   at_risk_i = sum over complement (incl. self) of exp(clip(lr_j,-10,10))
//               == cumsum(exp(slr)) of stable argsort(-times).
// grid (32 i-blocks, 8 j-chunks) x 256 thr.
// ---------------------------------------------------------------------------
__global__ void __launch_bounds__(256) k_rank_atrisk(
    const float* __restrict__ times, const float* __restrict__ lr,
    int* __restrict__ rank, float* __restrict__ at_risk) {
  __shared__ __align__(16) float st[1024];
  __shared__ __align__(16) float se[1024];
  const int tid = threadIdx.x;
  const int i = blockIdx.x * 256 + tid;
  const int jbase = blockIdx.y * 1024;
  for (int p = tid; p < 1024; p += 256) {
    float t = times[jbase + p];
    float l = lr[jbase + p];
    l = fminf(fmaxf(l, -10.f), 10.f);
    st[p] = t;
    se[p] = expf(l);
  }
  __syncthreads();
  const float ti = times[i];
  int rk = 0;
  float ar = 0.f;
  for (int p4 = 0; p4 < 1024; p4 += 4) {
    float4 tv = *(const float4*)&st[p4];
    float4 ev = *(const float4*)&se[p4];
    const int j0 = jbase + p4;
#define K1_STEP(c, jo)                                              \
    {                                                               \
      bool c1 = (c < ti) || ((c == ti) && ((j0 + jo) < i));         \
      rk += c1 ? 1 : 0;                                             \
      ar += c1 ? 0.f : ((jo == 0) ? ev.x : (jo == 1) ? ev.y         \
                         : (jo == 2) ? ev.z : ev.w);                \
    }
    K1_STEP(tv.x, 0) K1_STEP(tv.y, 1) K1_STEP(tv.z, 2) K1_STEP(tv.w, 3)
#undef K1_STEP
  }
  atomicAdd(&rank[i], rk);
  atomicAdd(&at_risk[i], ar);
}

// ---------------------------------------------------------------------------
// K2: per-row (one wave per row): norms, cos-sim term, Cox li term,
//     normalize -> bf16 -> scatter-write into rank-permuted packed layout.
// grid 2048 x 256 thr (4 waves). Block-reduce + 64-slot-spread atomics.
// ---------------------------------------------------------------------------
__global__ void __launch_bounds__(256) k_rows(
    const float* __restrict__ lr, const int* __restrict__ censor,
    const float* __restrict__ wsi, const float* __restrict__ omic,
    const int* __restrict__ rank, const float* __restrict__ at_risk,
    unsigned short* __restrict__ pw, unsigned short* __restrict__ po,
    float* __restrict__ slots) {
  __shared__ float red[4][3];
  const int tid = threadIdx.x;
  const int lane = tid & 63;
  const int wv = tid >> 6;
  const int i = blockIdx.x * 4 + wv;
  const float4 w = ((const float4*)(wsi + (size_t)i * DD))[lane];
  const float4 o = ((const float4*)(omic + (size_t)i * DD))[lane];
  float nw = w.x * w.x + w.y * w.y + w.z * w.z + w.w * w.w;
  float no = o.x * o.x + o.y * o.y + o.z * o.z + o.w * o.w;
  float dd = w.x * o.x + w.y * o.y + w.z * o.z + w.w * o.w;
  for (int m = 1; m < 64; m <<= 1) {
    nw += __shfl_xor(nw, m);
    no += __shfl_xor(no, m);
    dd += __shfl_xor(dd, m);
  }
  const float nws = sqrtf(nw), nos = sqrtf(no);
  if (lane == 0) {
    float c = dd / (fmaxf(nws, 1e-8f) * fmaxf(nos, 1e-8f));
    c = fminf(fmaxf(c, -1.f), 1.f);
    float l = fminf(fmaxf(lr[i], -10.f), 10.f);
    float li = l - logf(at_risk[i] + 1e-15f);
    bool cen = (censor[i] == 1);
    red[wv][0] = cen ? li : 0.f;   // cox sum
    red[wv][1] = cen ? 1.f : 0.f;  // count (exact in fp32)
    red[wv][2] = 1.f - c;          // sim sum
  }
  const int r = rank[i]; // permuted row position; rank>>11 == risk group
  const float iw = 1.f / fmaxf(nws, 1e-12f);
  const float io = 1.f / fmaxf(nos, 1e-12f);
  ushort4 zw, zo;
  zw.x = f2bf(w.x * iw); zw.y = f2bf(w.y * iw); zw.z = f2bf(w.z * iw); zw.w = f2bf(w.w * iw);
  zo.x = f2bf(o.x * io); zo.y = f2bf(o.y * io); zo.z = f2bf(o.z * io); zo.w = f2bf(o.w * io);
  // lane covers k = lane*4..lane*4+3 -> ks = lane>>3, offset (lane&7)*4 within 32-chunk
  const size_t off = ((size_t)(lane >> 3) * NN + r) * 32 + (lane & 7) * 4;
  *(ushort4*)(pw + off) = zw;
  *(ushort4*)(po + off) = zo;
  __syncthreads();
  if (tid < 3) {
    float v = red[0][tid] + red[1][tid] + red[2][tid] + red[3][tid];
    atomicAdd(&slots[tid * NSLOT + (blockIdx.x & (NSLOT - 1))], v);
  }
}

// ---------------------------------------------------------------------------
// K3: contrastive exp-sums. grid (8 colblk, 16 rowblk, 2 matrices) x 512 thr.
// Block = 512 rows x 1024 cols. Wave w owns rows [rowblk*512+w*64, +64),
// A register-resident (128 VGPR). B staged per block into double-buffered LDS
// (16 stages x 64 cols x 32 KB), consumed by all 8 waves -> B cache traffic
// 128 MB total (was 1 GB). Group is constant per block (1024-col range lies
// inside one 2048-col group): g = colblk>>1. Per-row exp-sums atomically
// added to gsum[matrix][row][group] (2-way contention).
//
// LDS layout (per buffer), 16-B units: unit(ct,ks,q,lo) = ((ct*8+ks)*4+q)*16+lo
//   ct=16-col tile in stage (0..3), ks=k/32 (0..7), q=lane>>4, lo=lane&15.
// Frag read for (ct,ks): offset = base(ct,ks) + lane*16B -> contiguous b128.
// Staging: wave w handles ks=w, lane l handles col cs+l: loads 64 B (4x16B
// chunks q=0..3) and ds_writes them to units (l>>4, w, q, l&15).
// ---------------------------------------------------------------------------
__global__ void __launch_bounds__(512, 2) k_contrast(
    const unsigned short* __restrict__ pw, const unsigned short* __restrict__ po,
    float* __restrict__ gsum) {
  __shared__ __align__(16) unsigned short sbuf[2][16384]; // 2 x 32 KB
  const int tid = threadIdx.x;
  const int lane = tid & 63;
  const int wv = tid >> 6;                 // 0..7 (= ks this wave stages)
  const int lo = lane & 15, q = lane >> 4; // MFMA frag coords
  const int cb = blockIdx.x, rb = blockIdx.y, mz = blockIdx.z;
  const unsigned short* __restrict__ pk = (mz == 0) ? pw : po;
  const int rowbase = rb * 512 + wv * 64;
  const int colstart = cb * 1024;
  const int g = cb >> 1; // risk group, constant for the whole block

  // A fragments: 4 row-tiles x 8 k-steps, register-resident
  bf16x8 afrag[4][8];
#pragma unroll
  for (int rt = 0; rt < 4; ++rt) {
    const size_t row = rowbase + rt * 16 + lo;
#pragma unroll
    for (int ks = 0; ks < 8; ++ks)
      afrag[rt][ks] = *(const bf16x8*)(pk + ((size_t)ks * NN + row) * 32 + q * 8);
  }

  const int sct = lane >> 4, slo = lane & 15; // staging coords (col tile, col-in-tile)

  // stage 0: load + write + barrier
  ush8 ld[4];
  {
    const unsigned short* src = pk + ((size_t)wv * NN + colstart + lane) * 32;
#pragma unroll
    for (int qq = 0; qq < 4; ++qq) ld[qq] = *(const ush8*)(src + qq * 8);
#pragma unroll
    for (int qq = 0; qq < 4; ++qq) {
      const int unit = ((sct * 8 + wv) * 4 + qq) * 16 + slo;
      *(ush8*)&sbuf[0][unit * 8] = ld[qq];
    }
  }
  __syncthreads();

  float s[4][4] = {{0.f}};

#pragma unroll 1
  for (int st = 0; st < 16; ++st) {
    // prefetch next stage into registers (lands during this stage's MFMAs)
    if (st < 15) {
      const unsigned short* src = pk + ((size_t)wv * NN + colstart + (st + 1) * 64 + lane) * 32;
#pragma unroll
      for (int qq = 0; qq < 4; ++qq) ld[qq] = *(const ush8*)(src + qq * 8);
    }
    const unsigned short* buf = sbuf[st & 1];
    const bool diagw = (rowbase == colstart + st * 64); // 64-aligned ranges: equal or disjoint
#pragma unroll
    for (int ct = 0; ct < 4; ++ct) {
      bf16x8 bf[8];
#pragma unroll
      for (int ks = 0; ks < 8; ++ks)
        bf[ks] = *(const bf16x8*)&buf[((((ct * 8 + ks) * 4 + q) * 16) + lo) * 8];
      f32x4 accv[4];
#pragma unroll
      for (int rt = 0; rt < 4; ++rt) { f32x4 z = {0.f, 0.f, 0.f, 0.f}; accv[rt] = z; }
#pragma unroll
      for (int ks = 0; ks < 8; ++ks)
#pragma unroll
        for (int rt = 0; rt < 4; ++rt)
          accv[rt] = __builtin_amdgcn_mfma_f32_16x16x32_bf16(afrag[rt][ks], bf[ks], accv[rt], 0, 0, 0);
#pragma unroll
      for (int rt = 0; rt < 4; ++rt)
#pragma unroll
        for (int r = 0; r < 4; ++r) {
          // sim = dot/0.1 <= 10 (unit vectors); fixed-shift softmax term
          float e = __expf(fmaf(accv[rt][r], 10.f, -10.f));
          if (ct == rt && diagw) {
            if (lo == q * 4 + r) e = 0.f; // exact diagonal exclusion
          }
          s[rt][r] += e;
        }
    }
    if (st < 15) {
#pragma unroll
      for (int qq = 0; qq < 4; ++qq) {
        const int unit = ((sct * 8 + wv) * 4 + qq) * 16 + slo;
        *(ush8*)&sbuf[(st + 1) & 1][unit * 8] = ld[qq];
      }
    }
    __syncthreads();
  }

  // flush: reduce each (rt,r) over the 16 col-lanes, one atomic per row
#pragma unroll
  for (int rt = 0; rt < 4; ++rt)
#pragma unroll
    for (int r = 0; r < 4; ++r) {
      float v = s[rt][r];
      for (int m = 1; m < 16; m <<= 1) v += __shfl_xor(v, m);
      if (lo == 0) {
        const int row = rowbase + rt * 16 + q * 4 + r; // C/D: row=(lane>>4)*4+reg
        atomicAdd(&gsum[(((size_t)mz * NN) + row) * 4 + g], v);
      }
    }
}

// ---------------------------------------------------------------------------
// K3b: per-row LSE-difference + reduce. 16384 entries. grid 64 x 256.
// loss_row = log(sum_all) - log(sum_posgroup)   (fixed shifts cancel)
// ---------------------------------------------------------------------------
__global__ void __launch_bounds__(256) k_lse(
    const float* __restrict__ gsum, float* __restrict__ slots) {
  __shared__ float r4[4];
  const int tid = threadIdx.x;
  const int lane = tid & 63, wv = tid >> 6;
  const int idx = blockIdx.x * 256 + tid; // (matrix, row) flattened
  const float4 v = ((const float4*)gsum)[idx];
  const int row = idx & (NN - 1);
  const int gg = row >> 11; // group of permuted row
  const float sg = (gg == 0) ? v.x : (gg == 1) ? v.y : (gg == 2) ? v.z : v.w;
  float loss = logf(v.x + v.y + v.z + v.w) - logf(sg);
  for (int m = 1; m < 64; m <<= 1) loss += __shfl_xor(loss, m);
  if (lane == 0) r4[wv] = loss;
  __syncthreads();
  if (tid == 0)
    atomicAdd(&slots[3 * NSLOT + (blockIdx.x & (NSLOT - 1))],
              r4[0] + r4[1] + r4[2] + r4[3]);
}

// ---------------------------------------------------------------------------
// K4: reduce 64 slots per quantity, combine scalar. One wave.
// ---------------------------------------------------------------------------
__global__ void k_final(const float* __restrict__ slots, float* __restrict__ out) {
  const int lane = threadIdx.x & 63;
  float cox_s = (lane < NSLOT) ? slots[0 * NSLOT + lane] : 0.f;
  float cnt_s = (lane < NSLOT) ? slots[1 * NSLOT + lane] : 0.f;
  float sim_s = (lane < NSLOT) ? slots[2 * NSLOT + lane] : 0.f;
  float con_s = (lane < NSLOT) ? slots[3 * NSLOT + lane] : 0.f;
  for (int m = 1; m < 64; m <<= 1) {
    cox_s += __shfl_xor(cox_s, m);
    cnt_s += __shfl_xor(cnt_s, m);
    sim_s += __shfl_xor(sim_s, m);
    con_s += __shfl_xor(con_s, m);
  }
  if (lane == 0) {
    float cnt = fmaxf(cnt_s, 1.f);
    float cox = -cox_s / cnt;
    float sim = sim_s / (float)NN;
    float contrast = 0.1f * 0.5f * con_s / (float)NN;
    out[0] = cox + sim + contrast;
  }
}

extern "C" void kernel_launch(void* const* d_in, const int* in_sizes, int n_in,
                              void* d_out, int out_size, void* d_ws, size_t ws_size,
                              hipStream_t stream) {
  const float* lr = (const float*)d_in[0];
  const float* times = (const float*)d_in[1];
  const int* censor = (const int*)d_in[2];
  const float* wsi = (const float*)d_in[3];
  const float* omic = (const float*)d_in[4];
  float* out = (float*)d_out;

  char* ws = (char*)d_ws;
  int* rank = (int*)ws;
  float* at_risk = (float*)(ws + 32768);
  float* slots = (float*)(ws + 65536);
  unsigned short* pw = (unsigned short*)(ws + 131072);
  unsigned short* po = (unsigned short*)(ws + 131072 + 4194304);
  float* gsum = (float*)(ws + 131072 + 8388608);

  hipMemsetAsync(d_ws, 0, 65536 + 4 * NSLOT * 4, stream);
  hipMemsetAsync(gsum, 0, (size_t)2 * NN * 4 * sizeof(float), stream);
  k_rank_atrisk<<<dim3(32, 8), 256, 0, stream>>>(times, lr, rank, at_risk);
  k_rows<<<2048, 256, 0, stream>>>(lr, censor, wsi, omic, rank, at_risk, pw, po, slots);
  k_contrast<<<dim3(8, 16, 2), 512, 0, stream>>>(pw, po, gsum);
  k_lse<<<64, 256, 0, stream>>>(gsum, slots);
  k_final<<<1, 64, 0, stream>>>(slots, out);
}

// Round 5
// 181.695 us; speedup vs baseline: 2.8323x; 1.1527x over previous
//
#include <hip/hip_runtime.h>

// JointLoss on MI355X. N=8192, D=256. Output: 1 fp32 scalar.
//
// ws layout (bytes):
//   [0,      32768)   rank[N] int (atomic-accumulated permutation 0..N-1)
//   [32768,  65536)   at_risk[N] float
//   [65536,  66560)   slots: 64 x 4 quantities (cox, cnt, sim, contrast)
//   [66560,  328704)  gsum[2][8192][4] float (per matrix,row,group exp-sums)
//   [393216, +4M)     packed wsi bf16, k-step-major pk[ks][row][32]
//   [393216+4M, +8M)  packed omic bf16
//
// R1: same-address atomics serialize -> slot-spread.
// R2: 64-row blocks streamed 1 GB of B from LLC -> latency-bound 100us.
// R3: 64-row A-residency = 128 VGPR -> 2 waves/SIMD, one barrier domain,
//     accvgpr traffic; 72us at 35-38% util. Now: 32-row waves (64 VGPR A),
//     2 blocks/CU (4 waves/SIMD), global_load_lds staging.
// R4: __exp2f name collides with glibc math.h macro internals -> __expf.

#define NN 8192
#define DD 256
#define NSLOT 64

typedef __attribute__((ext_vector_type(8))) short bf16x8; // 8 bf16 = 4 VGPRs
typedef __attribute__((ext_vector_type(4))) float f32x4;

__device__ inline unsigned short f2bf(float f) {
  union { float f; unsigned int u; } v;
  v.f = f;
  unsigned int u = v.u;
  unsigned int r = (u + 0x7fffu + ((u >> 16) & 1u)) >> 16; // RNE
  return (unsigned short)r;
}

__device__ inline void gl_lds16(const void* g, void* l) {
  // async 16B/lane global->LDS; LDS dst is wave-uniform base + lane*16
  __builtin_amdgcn_global_load_lds(
      (const __attribute__((address_space(1))) unsigned int*)g,
      (__attribute__((address_space(3))) unsigned int*)l, 16, 0, 0);
}

// ---------------------------------------------------------------------------
// K1: O(N^2) brute-force rank + at-risk sums (replaces sort+cumsum).
//   rank_i    = #{j : t_j < t_i or (t_j==t_i and j<i)}
//   at_risk_i = sum over complement (incl. self) of exp(clip(lr_j,-10,10))
// grid (32 i-blocks, 16 j-chunks) x 256 thr -> 2 blocks/CU.
// ---------------------------------------------------------------------------
__global__ void __launch_bounds__(256) k_rank_atrisk(
    const float* __restrict__ times, const float* __restrict__ lr,
    int* __restrict__ rank, float* __restrict__ at_risk) {
  __shared__ __align__(16) float st[512];
  __shared__ __align__(16) float se[512];
  const int tid = threadIdx.x;
  const int i = blockIdx.x * 256 + tid;
  const int jbase = blockIdx.y * 512;
  for (int p = tid; p < 512; p += 256) {
    float t = times[jbase + p];
    float l = lr[jbase + p];
    l = fminf(fmaxf(l, -10.f), 10.f);
    st[p] = t;
    se[p] = __expf(l);
  }
  __syncthreads();
  const float ti = times[i];
  int rk = 0;
  float ar = 0.f;
  for (int p4 = 0; p4 < 512; p4 += 4) {
    float4 tv = *(const float4*)&st[p4];
    float4 ev = *(const float4*)&se[p4];
    const int j0 = jbase + p4;
#define K1_STEP(c, jo)                                              \
    {                                                               \
      bool c1 = (c < ti) || ((c == ti) && ((j0 + jo) < i));         \
      rk += c1 ? 1 : 0;                                             \
      ar += c1 ? 0.f : ((jo == 0) ? ev.x : (jo == 1) ? ev.y         \
                         : (jo == 2) ? ev.z : ev.w);                \
    }
    K1_STEP(tv.x, 0) K1_STEP(tv.y, 1) K1_STEP(tv.z, 2) K1_STEP(tv.w, 3)
#undef K1_STEP
  }
  atomicAdd(&rank[i], rk);
  atomicAdd(&at_risk[i], ar);
}

// ---------------------------------------------------------------------------
// K2: per-row (one wave per row): norms, cos-sim, Cox li, normalize -> bf16
// -> scatter into rank-permuted packed layout. Block-reduce + slot atomics.
// ---------------------------------------------------------------------------
__global__ void __launch_bounds__(256) k_rows(
    const float* __restrict__ lr, const int* __restrict__ censor,
    const float* __restrict__ wsi, const float* __restrict__ omic,
    const int* __restrict__ rank, const float* __restrict__ at_risk,
    unsigned short* __restrict__ pw, unsigned short* __restrict__ po,
    float* __restrict__ slots) {
  __shared__ float red[4][3];
  const int tid = threadIdx.x;
  const int lane = tid & 63;
  const int wv = tid >> 6;
  const int i = blockIdx.x * 4 + wv;
  const float4 w = ((const float4*)(wsi + (size_t)i * DD))[lane];
  const float4 o = ((const float4*)(omic + (size_t)i * DD))[lane];
  float nw = w.x * w.x + w.y * w.y + w.z * w.z + w.w * w.w;
  float no = o.x * o.x + o.y * o.y + o.z * o.z + o.w * o.w;
  float dd = w.x * o.x + w.y * o.y + w.z * o.z + w.w * o.w;
  for (int m = 1; m < 64; m <<= 1) {
    nw += __shfl_xor(nw, m);
    no += __shfl_xor(no, m);
    dd += __shfl_xor(dd, m);
  }
  const float nws = sqrtf(nw), nos = sqrtf(no);
  if (lane == 0) {
    float c = dd / (fmaxf(nws, 1e-8f) * fmaxf(nos, 1e-8f));
    c = fminf(fmaxf(c, -1.f), 1.f);
    float l = fminf(fmaxf(lr[i], -10.f), 10.f);
    float li = l - logf(at_risk[i] + 1e-15f);
    bool cen = (censor[i] == 1);
    red[wv][0] = cen ? li : 0.f;
    red[wv][1] = cen ? 1.f : 0.f;
    red[wv][2] = 1.f - c;
  }
  const int r = rank[i]; // permuted row; rank>>11 == risk group
  const float iw = 1.f / fmaxf(nws, 1e-12f);
  const float io = 1.f / fmaxf(nos, 1e-12f);
  ushort4 zw, zo;
  zw.x = f2bf(w.x * iw); zw.y = f2bf(w.y * iw); zw.z = f2bf(w.z * iw); zw.w = f2bf(w.w * iw);
  zo.x = f2bf(o.x * io); zo.y = f2bf(o.y * io); zo.z = f2bf(o.z * io); zo.w = f2bf(o.w * io);
  // lane covers k = lane*4.. -> ks = lane>>3, offset (lane&7)*4 within 32-chunk
  const size_t off = ((size_t)(lane >> 3) * NN + r) * 32 + (lane & 7) * 4;
  *(ushort4*)(pw + off) = zw;
  *(ushort4*)(po + off) = zo;
  __syncthreads();
  if (tid < 3) {
    float v = red[0][tid] + red[1][tid] + red[2][tid] + red[3][tid];
    atomicAdd(&slots[tid * NSLOT + (blockIdx.x & (NSLOT - 1))], v);
  }
}

// ---------------------------------------------------------------------------
// K3: contrastive exp-sums. grid (8 cb, 32 rb, 2 mz) x 512 thr, 2 blocks/CU.
// Block = 256 rows x 1024 cols (16 stages x 64 cols). Wave owns 32 rows:
// afrag[2][8] = 64 VGPR register-resident. B staged via global_load_lds
// (async DMA, no VGPR round-trip) into double-buffered LDS (2x32KB).
//
// LDS unit layout (16B units): unit(ct,ks,q,lo) = ((ct*8+ks)*4+q)*16+lo.
// DMA writes are lane-linear: wave wv, chunk p covers units (wv*4+p)*64+lane;
// decoding u=(wv*4+p)*64+lane -> (ct=u>>9, ks=(u>>6)&7, q=(u>>4)&3, lo=u&15)
// gives the global source so DMA lands data exactly in frag-read order.
// Frag read (ct,ks): ds_read_b128 at unit base + lane (contiguous).
// Group constant per block (1024 cols inside one 2048-col group): g = cb>>1.
// ---------------------------------------------------------------------------
__global__ void __launch_bounds__(512, 4) k_contrast(
    const unsigned short* __restrict__ pw, const unsigned short* __restrict__ po,
    float* __restrict__ gsum) {
  __shared__ __align__(16) unsigned short sbuf[2][16384]; // 2 x 32 KB
  const int tid = threadIdx.x;
  const int lane = tid & 63;
  const int wv = tid >> 6;                 // 0..7
  const int lo = lane & 15, q = lane >> 4; // MFMA frag coords
  const int cb = blockIdx.x, rb = blockIdx.y, mz = blockIdx.z;
  const unsigned short* __restrict__ pk = (mz == 0) ? pw : po;
  const int rowbase = rb * 256 + wv * 32;
  const int colstart = cb * 1024;
  const int g = cb >> 1;

  // A fragments: 2 row-tiles x 8 k-steps = 64 VGPRs, register-resident
  bf16x8 afrag[2][8];
#pragma unroll
  for (int rt = 0; rt < 2; ++rt) {
    const size_t row = rowbase + rt * 16 + lo;
#pragma unroll
    for (int ks = 0; ks < 8; ++ks)
      afrag[rt][ks] = *(const bf16x8*)(pk + ((size_t)ks * NN + row) * 32 + q * 8);
  }

  // per-lane DMA source decode (constant across stages except +64 cols)
  const unsigned short* gsrc[4];
  unsigned short* ldst[4];
#pragma unroll
  for (int p = 0; p < 4; ++p) {
    const int u = (wv * 4 + p) * 64 + lane;
    const int cts = u >> 9, kss = (u >> 6) & 7, qs = (u >> 4) & 3, los = u & 15;
    gsrc[p] = pk + ((size_t)kss * NN + colstart + cts * 16 + los) * 32 + qs * 8;
    ldst[p] = &sbuf[0][(size_t)((wv * 4 + p) * 64) * 8];
  }
  // issue stage 0 DMA
#pragma unroll
  for (int p = 0; p < 4; ++p) gl_lds16(gsrc[p], ldst[p]);
  __syncthreads();

  float s[2][4] = {{0.f}};
  const int rtile = rowbase >> 6;
  const int dctbase = ((rowbase >> 5) & 1) ? 2 : 0; // 32-row wave within 64-block

#pragma unroll 1
  for (int st = 0; st < 16; ++st) {
    // async-prefetch next stage into the other buffer (drained at barrier)
    if (st < 15) {
      const size_t gadv = (size_t)(st + 1) * 64 * 32; // +64 cols
      unsigned short* lb = &sbuf[(st + 1) & 1][0];
#pragma unroll
      for (int p = 0; p < 4; ++p)
        gl_lds16(gsrc[p] + gadv, lb + (size_t)((wv * 4 + p) * 64) * 8);
    }
    const unsigned short* buf = &sbuf[st & 1][0];
    const bool diagw = (rtile == ((colstart + st * 64) >> 6));
#pragma unroll
    for (int ct = 0; ct < 4; ++ct) {
      f32x4 a0 = {0.f, 0.f, 0.f, 0.f}, a1 = {0.f, 0.f, 0.f, 0.f};
      // k-halves of 4 frags each: keeps bf at 16 VGPRs (fit 128-reg budget)
      bf16x8 bf[4];
#pragma unroll
      for (int ks = 0; ks < 4; ++ks)
        bf[ks] = *(const bf16x8*)&buf[(size_t)(((ct * 8 + ks) * 4 + q) * 16 + lo) * 8];
#pragma unroll
      for (int ks = 0; ks < 4; ++ks) {
        a0 = __builtin_amdgcn_mfma_f32_16x16x32_bf16(afrag[0][ks], bf[ks], a0, 0, 0, 0);
        a1 = __builtin_amdgcn_mfma_f32_16x16x32_bf16(afrag[1][ks], bf[ks], a1, 0, 0, 0);
      }
#pragma unroll
      for (int ks = 0; ks < 4; ++ks)
        bf[ks] = *(const bf16x8*)&buf[(size_t)(((ct * 8 + ks + 4) * 4 + q) * 16 + lo) * 8];
#pragma unroll
      for (int ks = 0; ks < 4; ++ks) {
        a0 = __builtin_amdgcn_mfma_f32_16x16x32_bf16(afrag[0][ks + 4], bf[ks], a0, 0, 0, 0);
        a1 = __builtin_amdgcn_mfma_f32_16x16x32_bf16(afrag[1][ks + 4], bf[ks], a1, 0, 0, 0);
      }
      // epilogue: exp(sim-10), sim = dot/0.1 (unit vectors => sim<=10)
#pragma unroll
      for (int r = 0; r < 4; ++r) {
        float e0 = __expf(fmaf(a0[r], 10.f, -10.f));
        float e1 = __expf(fmaf(a1[r], 10.f, -10.f));
        if (diagw) { // exact diagonal exclusion
          if (ct == dctbase + 0 && lo == q * 4 + r) e0 = 0.f;
          if (ct == dctbase + 1 && lo == q * 4 + r) e1 = 0.f;
        }
        s[0][r] += e0;
        s[1][r] += e1;
      }
    }
    __syncthreads();
  }

  // flush: reduce over 16 col-lanes, one atomic per (row, group)
#pragma unroll
  for (int rt = 0; rt < 2; ++rt)
#pragma unroll
    for (int r = 0; r < 4; ++r) {
      float v = s[rt][r];
      v += __shfl_xor(v, 1); v += __shfl_xor(v, 2);
      v += __shfl_xor(v, 4); v += __shfl_xor(v, 8);
      if (lo == 0) {
        const int row = rowbase + rt * 16 + q * 4 + r; // C/D: row=(lane>>4)*4+reg
        atomicAdd(&gsum[((size_t)mz * NN + row) * 4 + g], v);
      }
    }
}

// ---------------------------------------------------------------------------
// K3b: per-row LSE difference + reduce. loss = log(sum_all) - log(sum_pos).
// ---------------------------------------------------------------------------
__global__ void __launch_bounds__(256) k_lse(
    const float* __restrict__ gsum, float* __restrict__ slots) {
  __shared__ float r4[4];
  const int tid = threadIdx.x;
  const int lane = tid & 63, wv = tid >> 6;
  const int idx = blockIdx.x * 256 + tid; // (matrix, row) flattened
  const float4 v = ((const float4*)gsum)[idx];
  const int row = idx & (NN - 1);
  const int gg = row >> 11; // group of permuted row
  const float sg = (gg == 0) ? v.x : (gg == 1) ? v.y : (gg == 2) ? v.z : v.w;
  float loss = logf(v.x + v.y + v.z + v.w) - logf(sg);
  for (int m = 1; m < 64; m <<= 1) loss += __shfl_xor(loss, m);
  if (lane == 0) r4[wv] = loss;
  __syncthreads();
  if (tid == 0)
    atomicAdd(&slots[3 * NSLOT + (blockIdx.x & (NSLOT - 1))],
              r4[0] + r4[1] + r4[2] + r4[3]);
}

// ---------------------------------------------------------------------------
// K4: reduce slots, combine scalar.
// ---------------------------------------------------------------------------
__global__ void k_final(const float* __restrict__ slots, float* __restrict__ out) {
  const int lane = threadIdx.x & 63;
  float cox_s = (lane < NSLOT) ? slots[0 * NSLOT + lane] : 0.f;
  float cnt_s = (lane < NSLOT) ? slots[1 * NSLOT + lane] : 0.f;
  float sim_s = (lane < NSLOT) ? slots[2 * NSLOT + lane] : 0.f;
  float con_s = (lane < NSLOT) ? slots[3 * NSLOT + lane] : 0.f;
  for (int m = 1; m < 64; m <<= 1) {
    cox_s += __shfl_xor(cox_s, m);
    cnt_s += __shfl_xor(cnt_s, m);
    sim_s += __shfl_xor(sim_s, m);
    con_s += __shfl_xor(con_s, m);
  }
  if (lane == 0) {
    float cnt = fmaxf(cnt_s, 1.f);
    float cox = -cox_s / cnt;
    float sim = sim_s / (float)NN;
    float contrast = 0.1f * 0.5f * con_s / (float)NN;
    out[0] = cox + sim + contrast;
  }
}

extern "C" void kernel_launch(void* const* d_in, const int* in_sizes, int n_in,
                              void* d_out, int out_size, void* d_ws, size_t ws_size,
                              hipStream_t stream) {
  const float* lr = (const float*)d_in[0];
  const float* times = (const float*)d_in[1];
  const int* censor = (const int*)d_in[2];
  const float* wsi = (const float*)d_in[3];
  const float* omic = (const float*)d_in[4];
  float* out = (float*)d_out;

  char* ws = (char*)d_ws;
  int* rank = (int*)ws;
  float* at_risk = (float*)(ws + 32768);
  float* slots = (float*)(ws + 65536);
  float* gsum = (float*)(ws + 66560);
  unsigned short* pw = (unsigned short*)(ws + 393216);
  unsigned short* po = (unsigned short*)(ws + 393216 + 4194304);

  // one memset covers rank, at_risk, slots, gsum
  (void)hipMemsetAsync(d_ws, 0, 328704, stream);
  k_rank_atrisk<<<dim3(32, 16), 256, 0, stream>>>(times, lr, rank, at_risk);
  k_rows<<<2048, 256, 0, stream>>>(lr, censor, wsi, omic, rank, at_risk, pw, po, slots);
  k_contrast<<<dim3(8, 32, 2), 512, 0, stream>>>(pw, po, gsum);
  k_lse<<<64, 256, 0, stream>>>(gsum, slots);
  k_final<<<1, 64, 0, stream>>>(slots, out);
}